// Round 16
// baseline (215.910 us; speedup 1.0000x reference)
//
#include <hip/hip_runtime.h>
#include <cstdint>
#include <cmath>

typedef unsigned short u16;
typedef __bf16 bf16x8 __attribute__((ext_vector_type(8)));
typedef float  f32x4  __attribute__((ext_vector_type(4)));
typedef unsigned short u16x8 __attribute__((ext_vector_type(8)));

__device__ __forceinline__ u16 f2bf(float f) {
  unsigned u = __float_as_uint(f);
  u += 0x7fffu + ((u >> 16) & 1u);
  return (u16)(u >> 16);
}

#define NEG_BIG (-1.0e30f)

// async global->LDS, 16B per lane. LDS dest = wave-uniform base + lane*16.
__device__ __forceinline__ void gl_lds16(const void* g, void* l) {
  __builtin_amdgcn_global_load_lds(
      (const __attribute__((address_space(1))) unsigned*)g,
      (__attribute__((address_space(3))) unsigned*)l, 16, 0, 0);
}

// ---------------------------------------------------------------------------
// Bulk cast fp32 -> bf16 (8 elems/thread, coalesced). n must be /8/256.
// ---------------------------------------------------------------------------
__global__ __launch_bounds__(256) void cast_f2b(const float* __restrict__ in,
                                                u16* __restrict__ out) {
  const size_t i = ((size_t)blockIdx.x * 256 + threadIdx.x) * 8;
  const float* p = in + i;
  u16x8 hv;
#pragma unroll
  for (int j = 0; j < 8; ++j) hv[j] = f2bf(p[j]);
  *(u16x8*)(out + i) = hv;
}

// ---------------------------------------------------------------------------
// Transpose + cast fp32 -> bf16: in [R][C] fp32 -> out [C][R] bf16. [proven]
// ---------------------------------------------------------------------------
__global__ __launch_bounds__(256) void transpose_f2b(
    const float* __restrict__ in, u16* __restrict__ out, int R, int C) {
  __shared__ u16 t[64][65];
  const int c0 = blockIdx.x << 6, r0 = blockIdx.y << 6;
  const int x = threadIdx.x, y0 = threadIdx.y;
#pragma unroll
  for (int yy = 0; yy < 64; yy += 4)
    t[yy + y0][x] = f2bf(in[(size_t)(r0 + yy + y0) * C + c0 + x]);
  __syncthreads();
#pragma unroll
  for (int yy = 0; yy < 64; yy += 4)
    out[(size_t)(c0 + yy + y0) * R + r0 + x] = t[x][yy + y0];
}

// ---------------------------------------------------------------------------
// C[M,N] = A[M,K] @ Bt[N,K]^T + bias(fp32). Bt bf16, fp32 accum.
// Template NT = N-tile quarter-width: block covers 128 rows x NT*32 cols.
//   NT=4: 128x128 tile — byte-identical to the round-15 proven QKV path.
//   NT=2: 128x64 tile — doubles proj grid (8x32=256 -> 16x32=512 blocks,
//         1 -> 2 blocks/CU; proj was occupancy-starved at 1 blk/CU).
// !ADAPT_A: T4 counted-vmcnt pipeline [round-15 proven]: triple-buffer LDS,
// 2-deep gl_lds prefetch, per K-step wait only the oldest tile's loads
// (2A + NT/2 B = 4 or 3), raw s_barrier, STAGE(t+2), compute(t).
// ADAPT_A=1: proven reg-staged fallback (NT=4 only).
// MODE=1 epilogue byte-frozen (fragment-linear Q/K/V, multi-batch).
// ---------------------------------------------------------------------------
template <int MODE, int ADAPT_A, int NT>
__global__ __launch_bounds__(256, 2) void gemm_bt(
    const u16* __restrict__ A16, const float* __restrict__ AF,
    const u16* __restrict__ Bt, const float* __restrict__ biasF,
    float* __restrict__ out, u16* __restrict__ qb, u16* __restrict__ kb,
    u16* __restrict__ vt, int N, int K) {
  __shared__ u16 As[3][4096];
  __shared__ u16 Bs[3][NT * 1024];
  const int tid = threadIdx.x;
  const int lane = tid & 63;
  const int wave = tid >> 6;
  const int ln = lane & 15, quad = lane >> 4;
  const int wm = (wave >> 1) << 6, wn = (wave & 1) * (NT * 16);
  const int m0 = blockIdx.y << 7, n0 = blockIdx.x * (NT * 32);
  const int srow = tid >> 2, scol = (tid & 3) << 3;

  f32x4 acc[4][NT] = {};

  if (!ADAPT_A) {
    constexpr int RPW = NT / 2;  // B gl_lds calls per wave (rows/wave / 16)
    const u16* Arow =
        A16 + (size_t)(m0 + wave * 32 + (lane >> 2)) * K + (lane & 3) * 8;
    const u16* Brow = Bt +
                      (size_t)(n0 + wave * (16 * RPW) + (lane >> 2)) * K +
                      (lane & 3) * 8;
    const int nkt = K >> 5;
#define STAGE_GB(buf, k0)                                                   \
  {                                                                         \
    char* dA = (char*)&As[buf][0] + wave * 2048;                            \
    char* dB = (char*)&Bs[buf][0] + wave * (1024 * RPW);                    \
    _Pragma("unroll") for (int r = 0; r < 2; ++r)                           \
        gl_lds16(Arow + (k0) + (size_t)r * 16 * K, dA + r * 1024);          \
    _Pragma("unroll") for (int r = 0; r < RPW; ++r)                         \
        gl_lds16(Brow + (k0) + (size_t)r * 16 * K, dB + r * 1024);          \
  }
    STAGE_GB(0, 0);
    if (nkt > 1) STAGE_GB(1, 32);
    for (int t = 0; t < nkt; ++t) {
      const int cur = t % 3;
      // wait ONLY the oldest tile's (2+RPW) loads; newer stay in flight.
      if (t + 1 < nkt) {
        if constexpr (NT == 4)
          asm volatile("s_waitcnt vmcnt(4)" ::: "memory");
        else
          asm volatile("s_waitcnt vmcnt(3)" ::: "memory");
      } else {
        asm volatile("s_waitcnt vmcnt(0)" ::: "memory");
      }
      __builtin_amdgcn_s_barrier();  // raw: no compiler vmcnt(0) drain
      if (t + 2 < nkt) STAGE_GB((t + 2) % 3, (t + 2) << 5);
      bf16x8 af[4], bfr[NT];
#pragma unroll
      for (int tt = 0; tt < 4; ++tt)
        af[tt] = *(const bf16x8*)&As[cur][(wm + tt * 16 + ln) * 32 + quad * 8];
#pragma unroll
      for (int tt = 0; tt < NT; ++tt)
        bfr[tt] = *(const bf16x8*)&Bs[cur][(wn + tt * 16 + ln) * 32 + quad * 8];
#pragma unroll
      for (int mt = 0; mt < 4; ++mt)
#pragma unroll
        for (int nt2 = 0; nt2 < NT; ++nt2)
          acc[mt][nt2] = __builtin_amdgcn_mfma_f32_16x16x32_bf16(
              af[mt], bfr[nt2], acc[mt][nt2], 0, 0, 0);
    }
#undef STAGE_GB
  } else {
    for (int k0 = 0; k0 < K; k0 += 32) {
#pragma unroll
      for (int half = 0; half < 2; ++half) {
        const int arow = m0 + half * 64 + srow;
        u16* dstA = &As[0][half * 2048 + srow * 32 + scol];
        const float* p = AF + (size_t)arow * K + k0 + scol;
        u16x8 hv;
#pragma unroll
        for (int j = 0; j < 8; ++j) hv[j] = f2bf(p[j]);
        *(u16x8*)dstA = hv;
        const int brow = n0 + half * 64 + srow;
        *(u16x8*)&Bs[0][half * 2048 + srow * 32 + scol] =
            *(const u16x8*)(Bt + (size_t)brow * K + k0 + scol);
      }
      __syncthreads();
      bf16x8 af[4], bfr[4];
#pragma unroll
      for (int tt = 0; tt < 4; ++tt) {
        af[tt] = *(const bf16x8*)&As[0][(wm + tt * 16 + ln) * 32 + quad * 8];
        bfr[tt] = *(const bf16x8*)&Bs[0][(wn + tt * 16 + ln) * 32 + quad * 8];
      }
#pragma unroll
      for (int mt = 0; mt < 4; ++mt)
#pragma unroll
        for (int nt2 = 0; nt2 < NT; ++nt2)
          acc[mt][nt2] = __builtin_amdgcn_mfma_f32_16x16x32_bf16(
              af[mt], bfr[nt2], acc[mt][nt2], 0, 0, 0);
      __syncthreads();
    }
  }

#pragma unroll
  for (int mt = 0; mt < 4; ++mt) {
#pragma unroll
    for (int nt = 0; nt < NT; ++nt) {
      const int col = n0 + wn + nt * 16 + ln;
      const float bv = biasF[col];
      const int rbase = m0 + wm + mt * 16 + quad * 4;
      if (MODE == 0) {
#pragma unroll
        for (int r = 0; r < 4; ++r)
          out[(size_t)(rbase + r) * N + col] = acc[mt][nt][r] + bv;
      } else {
        const int c = col & 1023;
        const int which = col >> 10;
        const int h = c >> 6, d = c & 63;
        const int batch = rbase >> 11;       // rows 0..2047 = b0, 2048.. = b1
        const int sr = rbase & 2047;         // row within batch
        const size_t boff = (size_t)batch * 2097152;  // 16 heads * 131072
        // fragment-linear addressing (see attn_fwd header for layout)
        if (which == 0 || which == 1) {
          u16* dst = ((which == 0) ? qb : kb) + boff;
          const size_t base = (size_t)h * 131072 +
                              (size_t)(d >> 5) * 512 +
                              (size_t)((d >> 3) & 3) * 128 + (d & 7);
#pragma unroll
          for (int r = 0; r < 4; ++r) {
            const int s = sr + r;
            dst[base + (size_t)(s >> 4) * 1024 + (s & 15) * 8] =
                f2bf(acc[mt][nt][r] + bv);
          }
        } else {
          ushort4 pk;
          pk.x = f2bf(acc[mt][nt][0] + bv);
          pk.y = f2bf(acc[mt][nt][1] + bv);
          pk.z = f2bf(acc[mt][nt][2] + bv);
          pk.w = f2bf(acc[mt][nt][3] + bv);
          // V element (d, s): s = sr..sr+3 stay in one j-octet
          const size_t vaddr = boff + (size_t)h * 131072 +
                               (size_t)(sr >> 6) * 4096 +
                               (size_t)((sr >> 5) & 1) * 2048 +
                               (size_t)(d >> 4) * 512 +
                               (size_t)((sr >> 3) & 3) * 128 +
                               (d & 15) * 8 + (sr & 7);
          *(ushort4*)&vt[vaddr] = pk;
        }
      }
    }
  }
}

// ---------------------------------------------------------------------------
// Causal flash attention v11 [proven rounds 5-8, 10, 12, 15] + T5 setprio:
// FRAGMENT-LINEAR Q/K/V — each MFMA fragment (64 lanes x 8 bf16 = 1KB)
// stored contiguously in lane order; every fragment load is ONE coalesced
// 1KB wave-load. s_setprio(1) wraps the MFMA clusters (m191 regime match:
// independent waves, no barriers -> +4-7% measured there; pure hint).
// Layout per bh (131072 u16 each):
//   Q/K elem (s,d) -> (s>>4)*1024 + (d>>5)*512 + ((d>>3)&3)*128 + (s&15)*8 + (d&7)
//   V   elem (d,s) -> (s>>6)*4096 + ((s>>5)&1)*2048 + (d>>4)*512
//                     + ((s>>3)&3)*128 + (d&15)*8 + (s&7)
// launch_bounds (128,4): VGPR 64, zero spill. ATTN STRUCTURE IS FROZEN:
// latency-bound (round-14 A/B); 4-wave & split-K restructures all failed
// (rounds 2/3/9/11/13).
// ---------------------------------------------------------------------------
__global__ __launch_bounds__(128, 4) void attn_fwd(const u16* __restrict__ Qb,
                                                   const u16* __restrict__ Kb,
                                                   const u16* __restrict__ Vt,
                                                   u16* __restrict__ Y,
                                                   int lg_nbh) {
  __shared__ u16 P[2][1152];  // [wave][16 rows * 72]
  const int wave = threadIdx.x >> 6, lane = threadIdx.x & 63;
  const int ln = lane & 15, quad = lane >> 4;
  // --- XCD-aware decode (bijective remap of blockIdx.x) ---
  const int xcd = blockIdx.x & 7;
  const int rem = blockIdx.x >> 3;
  const int ppx_lg = lg_nbh - 4;  // log2(bh-pairs per XCD): 1 or 0
  const int p = (xcd << ppx_lg) | (rem & ((1 << ppx_lg) - 1));
  const int qtu = rem >> ppx_lg;                         // 0..127
  const int bh = (p << 1) + wave;
  const int qt = (qtu < 64) ? (127 - qtu) : (qtu - 64);  // heavy tasks first
  const int q0 = qt << 4;         // 16-row q-tile
  const int nch = (qt >> 2) + 1;  // 64-key chunks
  const u16* Qp = Qb + (size_t)bh * 131072;
  const u16* Kp = Kb + (size_t)bh * 131072;
  const u16* Vp = Vt + (size_t)bh * 131072;
  u16* Pw = P[wave];

  bf16x8 qf[2];
#pragma unroll
  for (int kk = 0; kk < 2; ++kk)
    qf[kk] = *(const bf16x8*)&Qp[qt * 1024 + kk * 512 + lane * 8];

  f32x4 o[4] = {};
  f32x4 l_run = {};

  const float cs = 0.18033688011112042f;  // log2(e) / sqrt(64)

  bf16x8 kf[4][2], kn[4][2];
  auto loadK = [&](bf16x8(&dst)[4][2], int kc) {
    const int ktb = kc << 2;
#pragma unroll
    for (int nt = 0; nt < 4; ++nt)
#pragma unroll
      for (int kk = 0; kk < 2; ++kk)
        dst[nt][kk] =
            *(const bf16x8*)&Kp[(ktb + nt) * 1024 + kk * 512 + lane * 8];
  };

  loadK(kf, 0);  // chunk-0 K fragments (always in-bounds)

  for (int kc = 0; kc < nch; ++kc) {
    const int k0 = kc << 6;
    const int last = (kc == nch - 1);
    const bool pre = (kc + 1 < nch);
    const int ant = last ? ((qt & 3) + 1) : 4;  // active 16-key tiles
    const int aks = (ant + 1) >> 1;             // active 32-key PV slices

    bf16x8 vf[4][2];
#pragma unroll
    for (int ks = 0; ks < 2; ++ks)
      if (ks < aks)
#pragma unroll
        for (int dt = 0; dt < 4; ++dt)
          vf[dt][ks] = *(const bf16x8*)&Vp[kc * 4096 + ks * 2048 + dt * 512 +
                                           lane * 8];

    if (pre) loadK(kn, kc + 1);  // next-chunk K

    f32x4 t[4] = {};  // zero-init: inactive tiles contribute p=0
    __builtin_amdgcn_s_setprio(1);
#pragma unroll
    for (int nt = 0; nt < 4; ++nt)
      if (nt < ant) {
        f32x4 s = {};
        s = __builtin_amdgcn_mfma_f32_16x16x32_bf16(qf[0], kf[nt][0], s, 0, 0,
                                                    0);
        s = __builtin_amdgcn_mfma_f32_16x16x32_bf16(qf[1], kf[nt][1], s, 0, 0,
                                                    0);
        t[nt] = s * cs;
      }
    __builtin_amdgcn_s_setprio(0);
#pragma unroll
    for (int nt = 0; nt < 4; ++nt)
      if (nt < ant) {
#pragma unroll
        for (int r = 0; r < 4; ++r) {
          if (last && (k0 + nt * 16 + ln > q0 + quad * 4 + r))
            t[nt][r] = NEG_BIG;                         // exp2 -> 0
          t[nt][r] = __builtin_amdgcn_exp2f(t[nt][r]);  // p in (0, ~2^14)
        }
        l_run += t[nt];  // order-free row-sum partial
      }

    // rotate prefetched K into place (last use of kf was above)
    if (pre) {
#pragma unroll
      for (int nt = 0; nt < 4; ++nt)
#pragma unroll
        for (int kk = 0; kk < 2; ++kk) kf[nt][kk] = kn[nt][kk];
    }

    // P (C-layout) -> LDS row-major [16 q][64 k], stride 72.
#pragma unroll
    for (int nt = 0; nt < 4; ++nt)
      if (nt < aks * 2)
#pragma unroll
        for (int r = 0; r < 4; ++r)
          Pw[(quad * 4 + r) * 72 + nt * 16 + ln] = f2bf(t[nt][r]);
    asm volatile("s_waitcnt lgkmcnt(0)" ::: "memory");  // own P writes done
    bf16x8 pa[2];
#pragma unroll
    for (int ks = 0; ks < 2; ++ks)
      if (ks < aks)
        pa[ks] = *(const bf16x8*)&Pw[ln * 72 + ks * 32 + quad * 8];
    __builtin_amdgcn_s_setprio(1);
#pragma unroll
    for (int dt = 0; dt < 4; ++dt)
#pragma unroll
      for (int ks = 0; ks < 2; ++ks)
        if (ks < aks)
          o[dt] = __builtin_amdgcn_mfma_f32_16x16x32_bf16(pa[ks], vf[dt][ks],
                                                          o[dt], 0, 0, 0);
    __builtin_amdgcn_s_setprio(0);
  }

  // one cross-lane row-sum reduce for l (16-lane groups)
#pragma unroll
  for (int off = 1; off < 16; off <<= 1)
#pragma unroll
    for (int c = 0; c < 4; ++c) l_run[c] += __shfl_xor(l_run[c], off);

  f32x4 inv;
#pragma unroll
  for (int c = 0; c < 4; ++c) inv[c] = 1.0f / l_run[c];
  const int b = bh >> 4, h = bh & 15;
#pragma unroll
  for (int dt = 0; dt < 4; ++dt) {
    const int col = h * 64 + dt * 16 + ln;
#pragma unroll
    for (int r = 0; r < 4; ++r) {
      const int srow = q0 + quad * 4 + r;
      Y[((size_t)(b * 2048 + srow)) * 1024 + col] = f2bf(o[dt][r] * inv[r]);
    }
  }
}

// ---------------------------------------------------------------------------
// Merged path (ws >= 32 MB): x pre-cast to bf16; ONE QKV gemm (M=4096,
// NT=4 counted-vmcnt pipeline); ONE attn launch (proven v11 + setprio);
// proj gemm NT=2 (128x64 tile, 512 blocks = 2/CU) writes fp32 DIRECTLY to
// d_out. Fallback: proven two-launch schedule.
// ---------------------------------------------------------------------------
extern "C" void kernel_launch(void* const* d_in, const int* in_sizes, int n_in,
                              void* d_out, int out_size, void* d_ws,
                              size_t ws_size, hipStream_t stream) {
  (void)in_sizes; (void)n_in; (void)out_size;
  const float* x  = (const float*)d_in[0];  // [2,2048,1024]
  const float* Wa = (const float*)d_in[1];  // [1024,3072]
  const float* ba = (const float*)d_in[2];  // [3072]
  const float* Wp = (const float*)d_in[3];  // [1024,1024]
  const float* bp = (const float*)d_in[4];  // [1024]

  char* ws = (char*)d_ws;
  char* outc = (char*)d_out;
  const size_t MB = 1024u * 1024u;

  if (ws_size >= 32 * MB) {
    u16* Q   = (u16*)(ws);             // [32][131072] (8 MB)
    u16* Kc  = (u16*)(ws + 8 * MB);    // (8 MB)
    u16* Vt  = (u16*)(ws + 16 * MB);   // (8 MB)
    u16* Yb  = (u16*)(ws + 24 * MB);   // [2][2048][1024] bf16 (8 MB)
    u16* WtP = (u16*)(ws);             // after attn (Q dead)
    u16* WtA = (u16*)(outc);           // 6 MB (dead after QKV gemm)
    u16* xb  = (u16*)(outc + 6 * MB);  // x as bf16 (dead after QKV gemm)

    transpose_f2b<<<dim3(48, 16), dim3(64, 4), 0, stream>>>(Wa, WtA, 1024,
                                                            3072);
    cast_f2b<<<dim3(2048), 256, 0, stream>>>(x, xb);  // 4096*1024 elems
    gemm_bt<1, 0, 4><<<dim3(24, 32), 256, 0, stream>>>(
        xb, nullptr, WtA, ba, nullptr, Q, Kc, Vt, 3072, 1024);
    attn_fwd<<<dim3(2048), 128, 0, stream>>>(Q, Kc, Vt, Yb, 5);
    transpose_f2b<<<dim3(16, 16), dim3(64, 4), 0, stream>>>(Wp, WtP, 1024,
                                                            1024);
    gemm_bt<0, 0, 2><<<dim3(16, 32), 256, 0, stream>>>(
        Yb, nullptr, WtP, bp, (float*)outc, nullptr, nullptr, nullptr, 1024,
        1024);
  } else {
    u16* Q   = (u16*)(ws);
    u16* Kc  = (u16*)(ws + 4 * MB);
    u16* Vt  = (u16*)(ws + 8 * MB);
    u16* WtP = (u16*)(ws);
    float* Cst = (float*)(ws + 4 * MB);
    u16* WtA = (u16*)(outc);
    u16* Y0  = (u16*)(outc + 6 * MB);
    u16* Y1  = (u16*)(outc + 10 * MB);

    transpose_f2b<<<dim3(48, 16), dim3(64, 4), 0, stream>>>(Wa, WtA, 1024,
                                                            3072);
    gemm_bt<1, 1, 4><<<dim3(24, 16), 256, 0, stream>>>(
        nullptr, x, WtA, ba, nullptr, Q, Kc, Vt, 3072, 1024);
    attn_fwd<<<dim3(1024), 128, 0, stream>>>(Q, Kc, Vt, Y0, 4);
    gemm_bt<1, 1, 4><<<dim3(24, 16), 256, 0, stream>>>(
        nullptr, x + (size_t)2048 * 1024, WtA, ba, nullptr, Q, Kc, Vt, 3072,
        1024);
    attn_fwd<<<dim3(1024), 128, 0, stream>>>(Q, Kc, Vt, Y1, 4);
    transpose_f2b<<<dim3(16, 16), dim3(64, 4), 0, stream>>>(Wp, WtP, 1024,
                                                            1024);
    gemm_bt<0, 0, 4><<<dim3(8, 16), 256, 0, stream>>>(
        Y0, nullptr, WtP, bp, Cst, nullptr, nullptr, nullptr, 1024, 1024);
    hipMemcpyAsync(outc, Cst, 8 * MB, hipMemcpyDeviceToDevice, stream);
    gemm_bt<0, 0, 4><<<dim3(8, 16), 256, 0, stream>>>(
        Y1, nullptr, WtP, bp, Cst, nullptr, nullptr, nullptr, 1024, 1024);
    hipMemcpyAsync(outc + 8 * MB, Cst, 8 * MB, hipMemcpyDeviceToDevice,
                   stream);
  }
}

// Round 17
// 181.423 us; speedup vs baseline: 1.1901x; 1.1901x over previous
//
#include <hip/hip_runtime.h>
#include <cstdint>
#include <cmath>

typedef unsigned short u16;
typedef __bf16 bf16x8 __attribute__((ext_vector_type(8)));
typedef float  f32x4  __attribute__((ext_vector_type(4)));
typedef unsigned short u16x8 __attribute__((ext_vector_type(8)));

__device__ __forceinline__ u16 f2bf(float f) {
  unsigned u = __float_as_uint(f);
  u += 0x7fffu + ((u >> 16) & 1u);
  return (u16)(u >> 16);
}

#define NEG_BIG (-1.0e30f)

// async global->LDS, 16B per lane. LDS dest = wave-uniform base + lane*16.
__device__ __forceinline__ void gl_lds16(const void* g, void* l) {
  __builtin_amdgcn_global_load_lds(
      (const __attribute__((address_space(1))) unsigned*)g,
      (__attribute__((address_space(3))) unsigned*)l, 16, 0, 0);
}

// ---------------------------------------------------------------------------
// Bulk cast fp32 -> bf16 (8 elems/thread, coalesced). n must be /8/256.
// ---------------------------------------------------------------------------
__global__ __launch_bounds__(256) void cast_f2b(const float* __restrict__ in,
                                                u16* __restrict__ out) {
  const size_t i = ((size_t)blockIdx.x * 256 + threadIdx.x) * 8;
  const float* p = in + i;
  u16x8 hv;
#pragma unroll
  for (int j = 0; j < 8; ++j) hv[j] = f2bf(p[j]);
  *(u16x8*)(out + i) = hv;
}

// ---------------------------------------------------------------------------
// Transpose + cast fp32 -> bf16: in [R][C] fp32 -> out [C][R] bf16. [proven]
// ---------------------------------------------------------------------------
__global__ __launch_bounds__(256) void transpose_f2b(
    const float* __restrict__ in, u16* __restrict__ out, int R, int C) {
  __shared__ u16 t[64][65];
  const int c0 = blockIdx.x << 6, r0 = blockIdx.y << 6;
  const int x = threadIdx.x, y0 = threadIdx.y;
#pragma unroll
  for (int yy = 0; yy < 64; yy += 4)
    t[yy + y0][x] = f2bf(in[(size_t)(r0 + yy + y0) * C + c0 + x]);
  __syncthreads();
#pragma unroll
  for (int yy = 0; yy < 64; yy += 4)
    out[(size_t)(c0 + yy + y0) * R + r0 + x] = t[x][yy + y0];
}

// ---------------------------------------------------------------------------
// C[M,N] = A[M,K] @ Bt[N,K]^T + bias(fp32). Bt bf16, fp32 accum.
// Template NT = N-tile quarter-width: block covers 128 rows x NT*32 cols.
//   NT=4: 128x128 tile — byte-identical to the round-15 proven QKV path.
//   NT=2: 128x64 tile — doubles proj grid (256 -> 512 blocks = 2/CU;
//         proj was occupancy-starved at 1 blk/CU; round-16: ~-7us).
// !ADAPT_A: T4 counted-vmcnt pipeline [rounds 15-16 proven]: triple-buffer
// LDS, 2-deep gl_lds prefetch, per K-step wait only the oldest tile's loads
// (2A + NT/2 B = 4 or 3), raw s_barrier, STAGE(t+2), compute(t).
// ADAPT_A=1: proven reg-staged fallback (NT=4 only).
// MODE=1 epilogue byte-frozen (fragment-linear Q/K/V, multi-batch).
// ---------------------------------------------------------------------------
template <int MODE, int ADAPT_A, int NT>
__global__ __launch_bounds__(256, 2) void gemm_bt(
    const u16* __restrict__ A16, const float* __restrict__ AF,
    const u16* __restrict__ Bt, const float* __restrict__ biasF,
    float* __restrict__ out, u16* __restrict__ qb, u16* __restrict__ kb,
    u16* __restrict__ vt, int N, int K) {
  __shared__ u16 As[3][4096];
  __shared__ u16 Bs[3][NT * 1024];
  const int tid = threadIdx.x;
  const int lane = tid & 63;
  const int wave = tid >> 6;
  const int ln = lane & 15, quad = lane >> 4;
  const int wm = (wave >> 1) << 6, wn = (wave & 1) * (NT * 16);
  const int m0 = blockIdx.y << 7, n0 = blockIdx.x * (NT * 32);
  const int srow = tid >> 2, scol = (tid & 3) << 3;

  f32x4 acc[4][NT] = {};

  if (!ADAPT_A) {
    constexpr int RPW = NT / 2;  // B gl_lds calls per wave (rows/wave / 16)
    const u16* Arow =
        A16 + (size_t)(m0 + wave * 32 + (lane >> 2)) * K + (lane & 3) * 8;
    const u16* Brow = Bt +
                      (size_t)(n0 + wave * (16 * RPW) + (lane >> 2)) * K +
                      (lane & 3) * 8;
    const int nkt = K >> 5;
#define STAGE_GB(buf, k0)                                                   \
  {                                                                         \
    char* dA = (char*)&As[buf][0] + wave * 2048;                            \
    char* dB = (char*)&Bs[buf][0] + wave * (1024 * RPW);                    \
    _Pragma("unroll") for (int r = 0; r < 2; ++r)                           \
        gl_lds16(Arow + (k0) + (size_t)r * 16 * K, dA + r * 1024);          \
    _Pragma("unroll") for (int r = 0; r < RPW; ++r)                         \
        gl_lds16(Brow + (k0) + (size_t)r * 16 * K, dB + r * 1024);          \
  }
    STAGE_GB(0, 0);
    if (nkt > 1) STAGE_GB(1, 32);
    for (int t = 0; t < nkt; ++t) {
      const int cur = t % 3;
      // wait ONLY the oldest tile's (2+RPW) loads; newer stay in flight.
      if (t + 1 < nkt) {
        if constexpr (NT == 4)
          asm volatile("s_waitcnt vmcnt(4)" ::: "memory");
        else
          asm volatile("s_waitcnt vmcnt(3)" ::: "memory");
      } else {
        asm volatile("s_waitcnt vmcnt(0)" ::: "memory");
      }
      __builtin_amdgcn_s_barrier();  // raw: no compiler vmcnt(0) drain
      if (t + 2 < nkt) STAGE_GB((t + 2) % 3, (t + 2) << 5);
      bf16x8 af[4], bfr[NT];
#pragma unroll
      for (int tt = 0; tt < 4; ++tt)
        af[tt] = *(const bf16x8*)&As[cur][(wm + tt * 16 + ln) * 32 + quad * 8];
#pragma unroll
      for (int tt = 0; tt < NT; ++tt)
        bfr[tt] = *(const bf16x8*)&Bs[cur][(wn + tt * 16 + ln) * 32 + quad * 8];
#pragma unroll
      for (int mt = 0; mt < 4; ++mt)
#pragma unroll
        for (int nt2 = 0; nt2 < NT; ++nt2)
          acc[mt][nt2] = __builtin_amdgcn_mfma_f32_16x16x32_bf16(
              af[mt], bfr[nt2], acc[mt][nt2], 0, 0, 0);
    }
#undef STAGE_GB
  } else {
    for (int k0 = 0; k0 < K; k0 += 32) {
#pragma unroll
      for (int half = 0; half < 2; ++half) {
        const int arow = m0 + half * 64 + srow;
        u16* dstA = &As[0][half * 2048 + srow * 32 + scol];
        const float* p = AF + (size_t)arow * K + k0 + scol;
        u16x8 hv;
#pragma unroll
        for (int j = 0; j < 8; ++j) hv[j] = f2bf(p[j]);
        *(u16x8*)dstA = hv;
        const int brow = n0 + half * 64 + srow;
        *(u16x8*)&Bs[0][half * 2048 + srow * 32 + scol] =
            *(const u16x8*)(Bt + (size_t)brow * K + k0 + scol);
      }
      __syncthreads();
      bf16x8 af[4], bfr[4];
#pragma unroll
      for (int tt = 0; tt < 4; ++tt) {
        af[tt] = *(const bf16x8*)&As[0][(wm + tt * 16 + ln) * 32 + quad * 8];
        bfr[tt] = *(const bf16x8*)&Bs[0][(wn + tt * 16 + ln) * 32 + quad * 8];
      }
#pragma unroll
      for (int mt = 0; mt < 4; ++mt)
#pragma unroll
        for (int nt2 = 0; nt2 < NT; ++nt2)
          acc[mt][nt2] = __builtin_amdgcn_mfma_f32_16x16x32_bf16(
              af[mt], bfr[nt2], acc[mt][nt2], 0, 0, 0);
      __syncthreads();
    }
  }

#pragma unroll
  for (int mt = 0; mt < 4; ++mt) {
#pragma unroll
    for (int nt = 0; nt < NT; ++nt) {
      const int col = n0 + wn + nt * 16 + ln;
      const float bv = biasF[col];
      const int rbase = m0 + wm + mt * 16 + quad * 4;
      if (MODE == 0) {
#pragma unroll
        for (int r = 0; r < 4; ++r)
          out[(size_t)(rbase + r) * N + col] = acc[mt][nt][r] + bv;
      } else {
        const int c = col & 1023;
        const int which = col >> 10;
        const int h = c >> 6, d = c & 63;
        const int batch = rbase >> 11;       // rows 0..2047 = b0, 2048.. = b1
        const int sr = rbase & 2047;         // row within batch
        const size_t boff = (size_t)batch * 2097152;  // 16 heads * 131072
        // fragment-linear addressing (see attn_fwd header for layout)
        if (which == 0 || which == 1) {
          u16* dst = ((which == 0) ? qb : kb) + boff;
          const size_t base = (size_t)h * 131072 +
                              (size_t)(d >> 5) * 512 +
                              (size_t)((d >> 3) & 3) * 128 + (d & 7);
#pragma unroll
          for (int r = 0; r < 4; ++r) {
            const int s = sr + r;
            dst[base + (size_t)(s >> 4) * 1024 + (s & 15) * 8] =
                f2bf(acc[mt][nt][r] + bv);
          }
        } else {
          ushort4 pk;
          pk.x = f2bf(acc[mt][nt][0] + bv);
          pk.y = f2bf(acc[mt][nt][1] + bv);
          pk.z = f2bf(acc[mt][nt][2] + bv);
          pk.w = f2bf(acc[mt][nt][3] + bv);
          // V element (d, s): s = sr..sr+3 stay in one j-octet
          const size_t vaddr = boff + (size_t)h * 131072 +
                               (size_t)(sr >> 6) * 4096 +
                               (size_t)((sr >> 5) & 1) * 2048 +
                               (size_t)(d >> 4) * 512 +
                               (size_t)((sr >> 3) & 3) * 128 +
                               (d & 15) * 8 + (sr & 7);
          *(ushort4*)&vt[vaddr] = pk;
        }
      }
    }
  }
}

// ---------------------------------------------------------------------------
// Causal flash attention v11 [proven rounds 5-8, 10, 12, 15 — FROZEN]:
// FRAGMENT-LINEAR Q/K/V — each MFMA fragment (64 lanes x 8 bf16 = 1KB)
// stored contiguously in lane order; every fragment load is ONE coalesced
// 1KB wave-load.  BYTE-EXACT round-15 form.  Change log (all reverted):
//   r9  forced launch_bounds(256,8) -> VGPR32 spill, 8x slower
//   r11 split-K natural regs       -> timing-dependent corruption
//   r13 4-wave same-bh packing     -> wrong results (class abandoned)
//   r14 2 q-tiles/wave             -> +17% (latency-bound, occupancy halved)
//   r16 setprio + MFMA/VALU split  -> 43->79us (broke compiler interleave;
//                                     setprio starves sibling wave: m190)
// Layout per bh (131072 u16 each):
//   Q/K elem (s,d) -> (s>>4)*1024 + (d>>5)*512 + ((d>>3)&3)*128 + (s&15)*8 + (d&7)
//   V   elem (d,s) -> (s>>6)*4096 + ((s>>5)&1)*2048 + (d>>4)*512
//                     + ((s>>3)&3)*128 + (d&15)*8 + (s&7)
// Consumer reads at tile_base + lane*8. launch_bounds (128,4): VGPR 64.
// ---------------------------------------------------------------------------
__global__ __launch_bounds__(128, 4) void attn_fwd(const u16* __restrict__ Qb,
                                                   const u16* __restrict__ Kb,
                                                   const u16* __restrict__ Vt,
                                                   u16* __restrict__ Y,
                                                   int lg_nbh) {
  __shared__ u16 P[2][1152];  // [wave][16 rows * 72]
  const int wave = threadIdx.x >> 6, lane = threadIdx.x & 63;
  const int ln = lane & 15, quad = lane >> 4;
  // --- XCD-aware decode (bijective remap of blockIdx.x) ---
  const int xcd = blockIdx.x & 7;
  const int rem = blockIdx.x >> 3;
  const int ppx_lg = lg_nbh - 4;  // log2(bh-pairs per XCD): 1 or 0
  const int p = (xcd << ppx_lg) | (rem & ((1 << ppx_lg) - 1));
  const int qtu = rem >> ppx_lg;                         // 0..127
  const int bh = (p << 1) + wave;
  const int qt = (qtu < 64) ? (127 - qtu) : (qtu - 64);  // heavy tasks first
  const int q0 = qt << 4;         // 16-row q-tile
  const int nch = (qt >> 2) + 1;  // 64-key chunks
  const u16* Qp = Qb + (size_t)bh * 131072;
  const u16* Kp = Kb + (size_t)bh * 131072;
  const u16* Vp = Vt + (size_t)bh * 131072;
  u16* Pw = P[wave];

  bf16x8 qf[2];
#pragma unroll
  for (int kk = 0; kk < 2; ++kk)
    qf[kk] = *(const bf16x8*)&Qp[qt * 1024 + kk * 512 + lane * 8];

  f32x4 o[4] = {};
  f32x4 l_run = {};

  const float cs = 0.18033688011112042f;  // log2(e) / sqrt(64)

  bf16x8 kf[4][2], kn[4][2];
  auto loadK = [&](bf16x8(&dst)[4][2], int kc) {
    const int ktb = kc << 2;
#pragma unroll
    for (int nt = 0; nt < 4; ++nt)
#pragma unroll
      for (int kk = 0; kk < 2; ++kk)
        dst[nt][kk] =
            *(const bf16x8*)&Kp[(ktb + nt) * 1024 + kk * 512 + lane * 8];
  };

  loadK(kf, 0);  // chunk-0 K fragments (always in-bounds)

  for (int kc = 0; kc < nch; ++kc) {
    const int k0 = kc << 6;
    const int last = (kc == nch - 1);
    const bool pre = (kc + 1 < nch);
    const int ant = last ? ((qt & 3) + 1) : 4;  // active 16-key tiles
    const int aks = (ant + 1) >> 1;             // active 32-key PV slices

    bf16x8 vf[4][2];
#pragma unroll
    for (int ks = 0; ks < 2; ++ks)
      if (ks < aks)
#pragma unroll
        for (int dt = 0; dt < 4; ++dt)
          vf[dt][ks] = *(const bf16x8*)&Vp[kc * 4096 + ks * 2048 + dt * 512 +
                                           lane * 8];

    if (pre) loadK(kn, kc + 1);  // next-chunk K

    f32x4 t[4] = {};  // zero-init: inactive tiles contribute p=0
#pragma unroll
    for (int nt = 0; nt < 4; ++nt)
      if (nt < ant) {
        f32x4 s = {};
        s = __builtin_amdgcn_mfma_f32_16x16x32_bf16(qf[0], kf[nt][0], s, 0, 0,
                                                    0);
        s = __builtin_amdgcn_mfma_f32_16x16x32_bf16(qf[1], kf[nt][1], s, 0, 0,
                                                    0);
        t[nt] = s * cs;
#pragma unroll
        for (int r = 0; r < 4; ++r) {
          if (last && (k0 + nt * 16 + ln > q0 + quad * 4 + r))
            t[nt][r] = NEG_BIG;                         // exp2 -> 0
          t[nt][r] = __builtin_amdgcn_exp2f(t[nt][r]);  // p in (0, ~2^14)
        }
        l_run += t[nt];  // order-free row-sum partial
      }

    // rotate prefetched K into place (last use of kf was above)
    if (pre) {
#pragma unroll
      for (int nt = 0; nt < 4; ++nt)
#pragma unroll
        for (int kk = 0; kk < 2; ++kk) kf[nt][kk] = kn[nt][kk];
    }

    // P (C-layout) -> LDS row-major [16 q][64 k], stride 72.
#pragma unroll
    for (int nt = 0; nt < 4; ++nt)
      if (nt < aks * 2)
#pragma unroll
        for (int r = 0; r < 4; ++r)
          Pw[(quad * 4 + r) * 72 + nt * 16 + ln] = f2bf(t[nt][r]);
    asm volatile("s_waitcnt lgkmcnt(0)" ::: "memory");  // own P writes done
    bf16x8 pa[2];
#pragma unroll
    for (int ks = 0; ks < 2; ++ks)
      if (ks < aks)
        pa[ks] = *(const bf16x8*)&Pw[ln * 72 + ks * 32 + quad * 8];
#pragma unroll
    for (int dt = 0; dt < 4; ++dt)
#pragma unroll
      for (int ks = 0; ks < 2; ++ks)
        if (ks < aks)
          o[dt] = __builtin_amdgcn_mfma_f32_16x16x32_bf16(pa[ks], vf[dt][ks],
                                                          o[dt], 0, 0, 0);
  }

  // one cross-lane row-sum reduce for l (16-lane groups)
#pragma unroll
  for (int off = 1; off < 16; off <<= 1)
#pragma unroll
    for (int c = 0; c < 4; ++c) l_run[c] += __shfl_xor(l_run[c], off);

  f32x4 inv;
#pragma unroll
  for (int c = 0; c < 4; ++c) inv[c] = 1.0f / l_run[c];
  const int b = bh >> 4, h = bh & 15;
#pragma unroll
  for (int dt = 0; dt < 4; ++dt) {
    const int col = h * 64 + dt * 16 + ln;
#pragma unroll
    for (int r = 0; r < 4; ++r) {
      const int srow = q0 + quad * 4 + r;
      Y[((size_t)(b * 2048 + srow)) * 1024 + col] = f2bf(o[dt][r] * inv[r]);
    }
  }
}

// ---------------------------------------------------------------------------
// Merged path (ws >= 32 MB): x pre-cast to bf16; ONE QKV gemm (M=4096,
// NT=4 counted-vmcnt pipeline); ONE attn launch (frozen v11); proj gemm
// NT=2 (128x64 tile, 512 blocks = 2/CU) writes fp32 DIRECTLY to d_out.
// Fallback: proven two-launch schedule.
// ---------------------------------------------------------------------------
extern "C" void kernel_launch(void* const* d_in, const int* in_sizes, int n_in,
                              void* d_out, int out_size, void* d_ws,
                              size_t ws_size, hipStream_t stream) {
  (void)in_sizes; (void)n_in; (void)out_size;
  const float* x  = (const float*)d_in[0];  // [2,2048,1024]
  const float* Wa = (const float*)d_in[1];  // [1024,3072]
  const float* ba = (const float*)d_in[2];  // [3072]
  const float* Wp = (const float*)d_in[3];  // [1024,1024]
  const float* bp = (const float*)d_in[4];  // [1024]

  char* ws = (char*)d_ws;
  char* outc = (char*)d_out;
  const size_t MB = 1024u * 1024u;

  if (ws_size >= 32 * MB) {
    u16* Q   = (u16*)(ws);             // [32][131072] (8 MB)
    u16* Kc  = (u16*)(ws + 8 * MB);    // (8 MB)
    u16* Vt  = (u16*)(ws + 16 * MB);   // (8 MB)
    u16* Yb  = (u16*)(ws + 24 * MB);   // [2][2048][1024] bf16 (8 MB)
    u16* WtP = (u16*)(ws);             // after attn (Q dead)
    u16* WtA = (u16*)(outc);           // 6 MB (dead after QKV gemm)
    u16* xb  = (u16*)(outc + 6 * MB);  // x as bf16 (dead after QKV gemm)

    transpose_f2b<<<dim3(48, 16), dim3(64, 4), 0, stream>>>(Wa, WtA, 1024,
                                                            3072);
    cast_f2b<<<dim3(2048), 256, 0, stream>>>(x, xb);  // 4096*1024 elems
    gemm_bt<1, 0, 4><<<dim3(24, 32), 256, 0, stream>>>(
        xb, nullptr, WtA, ba, nullptr, Q, Kc, Vt, 3072, 1024);
    attn_fwd<<<dim3(2048), 128, 0, stream>>>(Q, Kc, Vt, Yb, 5);
    transpose_f2b<<<dim3(16, 16), dim3(64, 4), 0, stream>>>(Wp, WtP, 1024,
                                                            1024);
    gemm_bt<0, 0, 2><<<dim3(16, 32), 256, 0, stream>>>(
        Yb, nullptr, WtP, bp, (float*)outc, nullptr, nullptr, nullptr, 1024,
        1024);
  } else {
    u16* Q   = (u16*)(ws);
    u16* Kc  = (u16*)(ws + 4 * MB);
    u16* Vt  = (u16*)(ws + 8 * MB);
    u16* WtP = (u16*)(ws);
    float* Cst = (float*)(ws + 4 * MB);
    u16* WtA = (u16*)(outc);
    u16* Y0  = (u16*)(outc + 6 * MB);
    u16* Y1  = (u16*)(outc + 10 * MB);

    transpose_f2b<<<dim3(48, 16), dim3(64, 4), 0, stream>>>(Wa, WtA, 1024,
                                                            3072);
    gemm_bt<1, 1, 4><<<dim3(24, 16), 256, 0, stream>>>(
        nullptr, x, WtA, ba, nullptr, Q, Kc, Vt, 3072, 1024);
    attn_fwd<<<dim3(1024), 128, 0, stream>>>(Q, Kc, Vt, Y0, 4);
    gemm_bt<1, 1, 4><<<dim3(24, 16), 256, 0, stream>>>(
        nullptr, x + (size_t)2048 * 1024, WtA, ba, nullptr, Q, Kc, Vt, 3072,
        1024);
    attn_fwd<<<dim3(1024), 128, 0, stream>>>(Q, Kc, Vt, Y1, 4);
    transpose_f2b<<<dim3(16, 16), dim3(64, 4), 0, stream>>>(Wp, WtP, 1024,
                                                            1024);
    gemm_bt<0, 0, 4><<<dim3(8, 16), 256, 0, stream>>>(
        Y0, nullptr, WtP, bp, Cst, nullptr, nullptr, nullptr, 1024, 1024);
    hipMemcpyAsync(outc, Cst, 8 * MB, hipMemcpyDeviceToDevice, stream);
    gemm_bt<0, 0, 4><<<dim3(8, 16), 256, 0, stream>>>(
        Y1, nullptr, WtP, bp, Cst, nullptr, nullptr, nullptr, 1024, 1024);
    hipMemcpyAsync(outc + 8 * MB, Cst, 8 * MB, hipMemcpyDeviceToDevice,
                   stream);
  }
}